// Round 1
// baseline (62036.621 us; speedup 1.0000x reference)
//
#include <hip/hip_runtime.h>

// Problem constants (from reference)
constexpr int N = 20000;
constexpr int E = 320000;
constexpr int B = 2;
constexpr int D = 64;
constexpr int L = 25;
constexpr float EPS = 1e-5f;

constexpr int WPB = 8;           // waves per block
constexpr int TPB = WPB * 64;    // 512 threads
constexpr int EPW = 4;           // edges per wave (register blocking)
constexpr int NPW = 4;           // nodes per wave

__device__ __forceinline__ float wave_sum64(float v) {
#pragma unroll
  for (int off = 32; off > 0; off >>= 1) v += __shfl_xor(v, off, 64);
  return v;
}

// ---------------- encoder: h = x @ enc_w + enc_b ----------------
__global__ __launch_bounds__(TPB) void encoder_kernel(
    const float* __restrict__ x, const float* __restrict__ enc_w,
    const float* __restrict__ enc_b, float* __restrict__ h) {
  int idx = blockIdx.x * blockDim.x + threadIdx.x;
  if (idx >= B * N * D) return;
  int j = idx & (D - 1);
  int bn = idx >> 6;
  const float* xp = x + (size_t)bn * 3;
  h[idx] = enc_b[j] + xp[0] * enc_w[j] + xp[1] * enc_w[D + j] + xp[2] * enc_w[2 * D + j];
}

// ---------------- edge MLP + atomic aggregation ----------------
__global__ __launch_bounds__(TPB) void edge_kernel(
    const float* __restrict__ h, float* __restrict__ aggr,
    const int* __restrict__ row, const int* __restrict__ col,
    const float* __restrict__ eattr,
    const float* __restrict__ w1, const float* __restrict__ b1,
    const float* __restrict__ g1, const float* __restrict__ be1,
    const float* __restrict__ w2, const float* __restrict__ b2) {
  // w1 packed: [k4][j][kk] with 132 k-rows (2 zero pad rows)
  __shared__ __align__(16) float w1p[33 * 256];   // 33 KB
  __shared__ __align__(16) float w2p[16 * 256];   // 16 KB
  __shared__ __align__(16) float cat_s[WPB][EPW][132];
  __shared__ __align__(16) float t_s[WPB][EPW][64];

  const int tid = threadIdx.x;
  const int lane = tid & 63;
  const int w = tid >> 6;

  for (int idx = tid; idx < 130 * 64; idx += TPB) {
    int k = idx >> 6, j = idx & 63;
    w1p[((k >> 2) << 8) + (j << 2) + (k & 3)] = w1[idx];
  }
  for (int idx = tid; idx < 2 * 64; idx += TPB) {   // zero pad k=130,131
    int k = 130 + (idx >> 6), j = idx & 63;
    w1p[((k >> 2) << 8) + (j << 2) + (k & 3)] = 0.f;
  }
  for (int idx = tid; idx < 64 * 64; idx += TPB) {
    int k = idx >> 6, j = idx & 63;
    w2p[((k >> 2) << 8) + (j << 2) + (k & 3)] = w2[idx];
  }
  const float b1v = b1[lane], g1v = g1[lane], be1v = be1[lane], b2v = b2[lane];
  __syncthreads();

  const int total = B * E;
  const int per_iter = gridDim.x * WPB * EPW;
  const int niter = (total + per_iter - 1) / per_iter;
  const int wave_global = blockIdx.x * WPB + w;

  for (int it = 0; it < niter; ++it) {
    const int base = (it * gridDim.x * WPB + wave_global) * EPW;

    // Stage cat = [h[row], h[col], edge_attr, 0, 0] per edge (per-wave LDS)
#pragma unroll
    for (int e = 0; e < EPW; ++e) {
      int i = base + e;
      if (i < total) {
        int g = (i >= E) ? 1 : 0;
        int ee = i - g * E;
        int r = row[ee], c = col[ee];
        cat_s[w][e][lane]      = h[((size_t)(g * N + r) << 6) + lane];
        cat_s[w][e][64 + lane] = h[((size_t)(g * N + c) << 6) + lane];
        if (lane < 2)      cat_s[w][e][128 + lane] = eattr[(size_t)ee * 2 + lane];
        else if (lane < 4) cat_s[w][e][128 + lane] = 0.f;
      }
    }
    // wave-lockstep: in-order LDS per wave, no cross-wave sharing -> no barrier

    // GEMV1: t = cat @ w1 + b1
    float t[EPW];
#pragma unroll
    for (int e = 0; e < EPW; ++e) t[e] = b1v;
    for (int k4 = 0; k4 < 33; ++k4) {
      const float4 wv = *(const float4*)&w1p[(k4 << 8) + (lane << 2)];
#pragma unroll
      for (int e = 0; e < EPW; ++e) {
        const float4 cv = *(const float4*)&cat_s[w][e][k4 << 2];
        t[e] = fmaf(cv.x, wv.x, t[e]);
        t[e] = fmaf(cv.y, wv.y, t[e]);
        t[e] = fmaf(cv.z, wv.z, t[e]);
        t[e] = fmaf(cv.w, wv.w, t[e]);
      }
    }

    // LN over 64 channels + relu, stage for GEMV2
#pragma unroll
    for (int e = 0; e < EPW; ++e) {
      float mu = wave_sum64(t[e]) * (1.f / 64.f);
      float dv = t[e] - mu;
      float var = wave_sum64(dv * dv) * (1.f / 64.f);
      float tn = dv * rsqrtf(var + EPS) * g1v + be1v;
      t_s[w][e][lane] = fmaxf(tn, 0.f);
    }

    // GEMV2: m = t @ w2 + b2
    float m[EPW];
#pragma unroll
    for (int e = 0; e < EPW; ++e) m[e] = b2v;
    for (int k4 = 0; k4 < 16; ++k4) {
      const float4 wv = *(const float4*)&w2p[(k4 << 8) + (lane << 2)];
#pragma unroll
      for (int e = 0; e < EPW; ++e) {
        const float4 tv = *(const float4*)&t_s[w][e][k4 << 2];
        m[e] = fmaf(tv.x, wv.x, m[e]);
        m[e] = fmaf(tv.y, wv.y, m[e]);
        m[e] = fmaf(tv.z, wv.z, m[e]);
        m[e] = fmaf(tv.w, wv.w, m[e]);
      }
    }

    // segment_sum via coalesced atomics
#pragma unroll
    for (int e = 0; e < EPW; ++e) {
      int i = base + e;
      if (i < total) {
        int g = (i >= E) ? 1 : 0;
        int ee = i - g * E;
        atomicAdd(&aggr[((size_t)(g * N + row[ee]) << 6) + lane], m[e]);
      }
    }
  }
}

// ---------------- node update: h += relu(LN([h,aggr]@uw+ub)) ----------------
__global__ __launch_bounds__(TPB) void node_kernel(
    float* __restrict__ h, const float* __restrict__ aggr,
    const float* __restrict__ uw, const float* __restrict__ ub,
    const float* __restrict__ ug, const float* __restrict__ ube) {
  __shared__ __align__(16) float wp[32 * 256];   // 32 KB
  __shared__ __align__(16) float cat_s[WPB][NPW][128];
  const int tid = threadIdx.x;
  const int lane = tid & 63;
  const int w = tid >> 6;

  for (int idx = tid; idx < 128 * 64; idx += TPB) {
    int k = idx >> 6, j = idx & 63;
    wp[((k >> 2) << 8) + (j << 2) + (k & 3)] = uw[idx];
  }
  const float ubv = ub[lane], ugv = ug[lane], ubev = ube[lane];
  __syncthreads();

  const int total = B * N;
  const int per_iter = gridDim.x * WPB * NPW;
  const int niter = (total + per_iter - 1) / per_iter;
  const int wave_global = blockIdx.x * WPB + w;

  for (int it = 0; it < niter; ++it) {
    const int base = (it * gridDim.x * WPB + wave_global) * NPW;
#pragma unroll
    for (int e = 0; e < NPW; ++e) {
      int i = base + e;
      if (i < total) {
        cat_s[w][e][lane]      = h[((size_t)i << 6) + lane];
        cat_s[w][e][64 + lane] = aggr[((size_t)i << 6) + lane];
      }
    }
    float t[NPW];
#pragma unroll
    for (int e = 0; e < NPW; ++e) t[e] = ubv;
    for (int k4 = 0; k4 < 32; ++k4) {
      const float4 wv = *(const float4*)&wp[(k4 << 8) + (lane << 2)];
#pragma unroll
      for (int e = 0; e < NPW; ++e) {
        const float4 cv = *(const float4*)&cat_s[w][e][k4 << 2];
        t[e] = fmaf(cv.x, wv.x, t[e]);
        t[e] = fmaf(cv.y, wv.y, t[e]);
        t[e] = fmaf(cv.z, wv.z, t[e]);
        t[e] = fmaf(cv.w, wv.w, t[e]);
      }
    }
#pragma unroll
    for (int e = 0; e < NPW; ++e) {
      float mu = wave_sum64(t[e]) * (1.f / 64.f);
      float dv = t[e] - mu;
      float var = wave_sum64(dv * dv) * (1.f / 64.f);
      float tn = dv * rsqrtf(var + EPS) * ugv + ubev;
      float u = fmaxf(tn, 0.f);
      int i = base + e;
      if (i < total) h[((size_t)i << 6) + lane] += u;
    }
  }
}

// ---------------- decoder: out = relu(h@dw1+db1)@dw2+db2 ----------------
__global__ __launch_bounds__(TPB) void decoder_kernel(
    const float* __restrict__ h,
    const float* __restrict__ dw1, const float* __restrict__ db1,
    const float* __restrict__ dw2, const float* __restrict__ db2,
    float* __restrict__ out) {
  __shared__ __align__(16) float w1s[64 * 32];
  __shared__ float w2s[64];
  __shared__ float b1s[32];
  __shared__ float hs[WPB][64];
  const int tid = threadIdx.x;
  const int lane = tid & 63;
  const int w = tid >> 6;

  for (int idx = tid; idx < 64 * 32; idx += TPB) w1s[idx] = dw1[idx];
  if (tid < 64) w2s[tid] = dw2[tid];
  if (tid < 32) b1s[tid] = db1[tid];
  const float ob0 = db2[0], ob1 = db2[1];
  __syncthreads();

  const int total = B * N;
  const int per_iter = gridDim.x * WPB;
  const int niter = (total + per_iter - 1) / per_iter;
  const int wave_global = blockIdx.x * WPB + w;

  for (int it = 0; it < niter; ++it) {
    const int i = it * per_iter + wave_global;
    if (i < total) {
      hs[w][lane] = h[((size_t)i << 6) + lane];
      float s1 = 0.f;
      if (lane < 32) {
        s1 = b1s[lane];
        for (int k = 0; k < 64; ++k) s1 = fmaf(hs[w][k], w1s[k * 32 + lane], s1);
        s1 = fmaxf(s1, 0.f);
      }
      float c0 = (lane < 32) ? s1 * w2s[lane * 2]     : 0.f;
      float c1 = (lane < 32) ? s1 * w2s[lane * 2 + 1] : 0.f;
#pragma unroll
      for (int off = 16; off > 0; off >>= 1) {
        c0 += __shfl_xor(c0, off, 64);
        c1 += __shfl_xor(c1, off, 64);
      }
      if (lane == 0) {
        out[(size_t)i * 2]     = c0 + ob0;
        out[(size_t)i * 2 + 1] = c1 + ob1;
      }
    }
  }
}

extern "C" void kernel_launch(void* const* d_in, const int* in_sizes, int n_in,
                              void* d_out, int out_size, void* d_ws, size_t ws_size,
                              hipStream_t stream) {
  const float* x        = (const float*)d_in[0];
  const int*   ei       = (const int*)d_in[1];
  const float* eattr    = (const float*)d_in[2];
  const float* enc_w    = (const float*)d_in[3];
  const float* enc_b    = (const float*)d_in[4];
  const float* msg_w1   = (const float*)d_in[5];
  const float* msg_b1   = (const float*)d_in[6];
  const float* msg_ln_g = (const float*)d_in[7];
  const float* msg_ln_b = (const float*)d_in[8];
  const float* msg_w2   = (const float*)d_in[9];
  const float* msg_b2   = (const float*)d_in[10];
  const float* up_w     = (const float*)d_in[11];
  const float* up_b     = (const float*)d_in[12];
  const float* up_ln_g  = (const float*)d_in[13];
  const float* up_ln_b  = (const float*)d_in[14];
  const float* dw1      = (const float*)d_in[15];
  const float* db1      = (const float*)d_in[16];
  const float* dw2      = (const float*)d_in[17];
  const float* db2      = (const float*)d_in[18];
  float* out = (float*)d_out;

  float* h    = (float*)d_ws;
  float* aggr = h + (size_t)B * N * D;

  const int* row = ei;       // edge_index[0]
  const int* col = ei + E;   // edge_index[1]

  encoder_kernel<<<(B * N * D + TPB - 1) / TPB, TPB, 0, stream>>>(x, enc_w, enc_b, h);

  for (int l = 0; l < L; ++l) {
    hipMemsetAsync(aggr, 0, (size_t)B * N * D * sizeof(float), stream);
    edge_kernel<<<512, TPB, 0, stream>>>(
        h, aggr, row, col, eattr,
        msg_w1 + (size_t)l * 130 * 64, msg_b1 + l * 64,
        msg_ln_g + l * 64, msg_ln_b + l * 64,
        msg_w2 + (size_t)l * 64 * 64, msg_b2 + l * 64);
    node_kernel<<<256, TPB, 0, stream>>>(
        h, aggr,
        up_w + (size_t)l * 128 * 64, up_b + l * 64,
        up_ln_g + l * 64, up_ln_b + l * 64);
  }

  decoder_kernel<<<512, TPB, 0, stream>>>(h, dw1, db1, dw2, db2, out);
}

// Round 2
// 24652.533 us; speedup vs baseline: 2.5164x; 2.5164x over previous
//
#include <hip/hip_runtime.h>

constexpr int N = 20000;
constexpr int E = 320000;
constexpr int B = 2;
constexpr int D = 64;
constexpr int L = 25;
constexpr float EPS = 1e-5f;

constexpr int WPB = 16;          // waves per block (layer kernel)
constexpr int TPB = WPB * 64;    // 1024 threads
constexpr int EPW = 4;           // edges per wave register block

__device__ __forceinline__ float wave_sum64(float v) {
#pragma unroll
  for (int off = 32; off > 0; off >>= 1) v += __shfl_xor(v, off, 64);
  return v;
}

// ---------------- CSR build (once per launch) ----------------
__global__ void hist_kernel(const int* __restrict__ row, int* __restrict__ deg) {
  int e = blockIdx.x * blockDim.x + threadIdx.x;
  if (e < E) atomicAdd(&deg[row[e]], 1);
}

__global__ __launch_bounds__(1024) void scan_kernel(const int* __restrict__ deg,
                                                    int* __restrict__ row_start,
                                                    int* __restrict__ cursor) {
  __shared__ int s[1024];
  const int t = threadIdx.x;
  constexpr int CH = (N + 1023) / 1024;  // 20
  int base = t * CH;
  int sum = 0;
  for (int k = 0; k < CH; ++k) {
    int idx = base + k;
    if (idx < N) sum += deg[idx];
  }
  s[t] = sum;
  __syncthreads();
  for (int off = 1; off < 1024; off <<= 1) {
    int v = (t >= off) ? s[t - off] : 0;
    __syncthreads();
    s[t] += v;
    __syncthreads();
  }
  int excl = s[t] - sum;
  for (int k = 0; k < CH; ++k) {
    int idx = base + k;
    if (idx < N) {
      row_start[idx] = excl;
      cursor[idx] = excl;
      excl += deg[idx];
    }
  }
  if (t == 1023) row_start[N] = s[1023];  // == E
}

__global__ void scatter_kernel(const int* __restrict__ row, int* __restrict__ cursor,
                               int* __restrict__ edge_order) {
  int e = blockIdx.x * blockDim.x + threadIdx.x;
  if (e < E) {
    int p = atomicAdd(&cursor[row[e]], 1);
    edge_order[p] = e;
  }
}

// ---------------- encoder: h = x @ enc_w + enc_b ----------------
__global__ __launch_bounds__(512) void encoder_kernel(
    const float* __restrict__ x, const float* __restrict__ enc_w,
    const float* __restrict__ enc_b, float* __restrict__ h) {
  int idx = blockIdx.x * blockDim.x + threadIdx.x;
  if (idx >= B * N * D) return;
  int j = idx & (D - 1);
  int bn = idx >> 6;
  const float* xp = x + (size_t)bn * 3;
  h[idx] = enc_b[j] + xp[0] * enc_w[j] + xp[1] * enc_w[D + j] + xp[2] * enc_w[2 * D + j];
}

// ---------------- fused layer: edge MLP + aggregate + node update ----------------
// One wave per node; CSR edge list; no atomics; h_old -> h_new (ping-pong).
__global__ __launch_bounds__(TPB, 4) void layer_kernel(
    const float* __restrict__ h_old, float* __restrict__ h_new,
    const int* __restrict__ col, const float* __restrict__ eattr,
    const int* __restrict__ row_start, const int* __restrict__ edge_order,
    const float* __restrict__ w1, const float* __restrict__ b1,
    const float* __restrict__ g1, const float* __restrict__ be1,
    const float* __restrict__ w2, const float* __restrict__ b2,
    const float* __restrict__ uw, const float* __restrict__ ub,
    const float* __restrict__ ug, const float* __restrict__ ube) {
  // weights packed by k-quads: [k>>2][j][k&3] -> float4 per (k4, lane)
  __shared__ __align__(16) float w1p[33 * 256];   // rows 0..129 + 2 zero rows
  __shared__ __align__(16) float w2p[16 * 256];
  __shared__ __align__(16) float uwp[32 * 256];
  __shared__ __align__(16) float hn_s[WPB][64];
  __shared__ __align__(16) float hc_s[WPB][EPW][68];  // h[col] (64) + eattr (2) + pad
  __shared__ __align__(16) float t_s[WPB][EPW][64];

  const int tid = threadIdx.x;
  const int lane = tid & 63;
  const int w = tid >> 6;

  for (int idx = tid; idx < 130 * 64; idx += TPB) {
    int k = idx >> 6, j = idx & 63;
    w1p[((k >> 2) << 8) + (j << 2) + (k & 3)] = w1[idx];
  }
  for (int idx = tid; idx < 2 * 64; idx += TPB) {  // zero pad rows 130,131
    int k = 130 + (idx >> 6), j = idx & 63;
    w1p[((k >> 2) << 8) + (j << 2) + (k & 3)] = 0.f;
  }
  for (int idx = tid; idx < 64 * 64; idx += TPB) {
    int k = idx >> 6, j = idx & 63;
    w2p[((k >> 2) << 8) + (j << 2) + (k & 3)] = w2[idx];
  }
  for (int idx = tid; idx < 128 * 64; idx += TPB) {
    int k = idx >> 6, j = idx & 63;
    uwp[((k >> 2) << 8) + (j << 2) + (k & 3)] = uw[idx];
  }
  const float b1v = b1[lane], g1v = g1[lane], be1v = be1[lane], b2v = b2[lane];
  const float ubv = ub[lane], ugv = ug[lane], ubev = ube[lane];
  __syncthreads();

  const int i = blockIdx.x * WPB + w;  // global node slot in [0, B*N)
  if (i >= B * N) return;              // no further barriers below
  const int g = (i >= N) ? 1 : 0;
  const int n = i - g * N;
  const size_t hbase = (size_t)g * N * 64;

  const float hnl = h_old[((size_t)i << 6) + lane];
  hn_s[w][lane] = hnl;  // wave-local, in-order LDS: no barrier needed

  // t0 = b1 + (h[n] part of GEMV1)  -- shared by all edges of this node
  float t0 = b1v;
#pragma unroll
  for (int q = 0; q < 16; ++q) {
    const float4 wv = *(const float4*)&w1p[(q << 8) + (lane << 2)];
    const float4 hv = *(const float4*)&hn_s[w][q << 2];
    t0 = fmaf(hv.x, wv.x, t0); t0 = fmaf(hv.y, wv.y, t0);
    t0 = fmaf(hv.z, wv.z, t0); t0 = fmaf(hv.w, wv.w, t0);
  }

  float acc = 0.f;
  const int es = row_start[n], ee = row_start[n + 1];
  for (int p = es; p < ee; p += EPW) {
    const int m = min(EPW, ee - p);
    int eid = 0, cc = 0;
    if (lane < m) { eid = edge_order[p + lane]; cc = col[eid]; }
#pragma unroll
    for (int e = 0; e < EPW; ++e) {
      if (e < m) {
        const int ce = __shfl(cc, e, 64);
        const int ei_ = __shfl(eid, e, 64);
        hc_s[w][e][lane] = h_old[hbase + ((size_t)ce << 6) + lane];
        if (lane < 2)      hc_s[w][e][64 + lane] = eattr[(size_t)ei_ * 2 + lane];
        else if (lane < 4) hc_s[w][e][64 + lane] = 0.f;
      }
    }
    // GEMV1 (h[col] + eattr part), e>=m computes garbage but is discarded
    float t[EPW];
#pragma unroll
    for (int e = 0; e < EPW; ++e) t[e] = t0;
    for (int q = 0; q < 17; ++q) {
      const float4 wv = *(const float4*)&w1p[((16 + q) << 8) + (lane << 2)];
#pragma unroll
      for (int e = 0; e < EPW; ++e) {
        const float4 cv = *(const float4*)&hc_s[w][e][q << 2];
        t[e] = fmaf(cv.x, wv.x, t[e]); t[e] = fmaf(cv.y, wv.y, t[e]);
        t[e] = fmaf(cv.z, wv.z, t[e]); t[e] = fmaf(cv.w, wv.w, t[e]);
      }
    }
#pragma unroll
    for (int e = 0; e < EPW; ++e) {
      float mu = wave_sum64(t[e]) * (1.f / 64.f);
      float dv = t[e] - mu;
      float var = wave_sum64(dv * dv) * (1.f / 64.f);
      float tn = dv * rsqrtf(var + EPS) * g1v + be1v;
      t_s[w][e][lane] = fmaxf(tn, 0.f);
    }
    float mm[EPW];
#pragma unroll
    for (int e = 0; e < EPW; ++e) mm[e] = b2v;
    for (int q = 0; q < 16; ++q) {
      const float4 wv = *(const float4*)&w2p[(q << 8) + (lane << 2)];
#pragma unroll
      for (int e = 0; e < EPW; ++e) {
        const float4 tv = *(const float4*)&t_s[w][e][q << 2];
        mm[e] = fmaf(tv.x, wv.x, mm[e]); mm[e] = fmaf(tv.y, wv.y, mm[e]);
        mm[e] = fmaf(tv.z, wv.z, mm[e]); mm[e] = fmaf(tv.w, wv.w, mm[e]);
      }
    }
#pragma unroll
    for (int e = 0; e < EPW; ++e)
      if (e < m) acc += mm[e];
  }

  // node update: u = relu(LN([h[n], aggr] @ uw + ub)); h_new = h + u
  hc_s[w][0][lane] = acc;  // reuse as aggregate staging (wave-local)
  float t = ubv;
#pragma unroll
  for (int q = 0; q < 16; ++q) {
    const float4 wv = *(const float4*)&uwp[(q << 8) + (lane << 2)];
    const float4 hv = *(const float4*)&hn_s[w][q << 2];
    t = fmaf(hv.x, wv.x, t); t = fmaf(hv.y, wv.y, t);
    t = fmaf(hv.z, wv.z, t); t = fmaf(hv.w, wv.w, t);
  }
#pragma unroll
  for (int q = 0; q < 16; ++q) {
    const float4 wv = *(const float4*)&uwp[((16 + q) << 8) + (lane << 2)];
    const float4 av = *(const float4*)&hc_s[w][0][q << 2];
    t = fmaf(av.x, wv.x, t); t = fmaf(av.y, wv.y, t);
    t = fmaf(av.z, wv.z, t); t = fmaf(av.w, wv.w, t);
  }
  float mu = wave_sum64(t) * (1.f / 64.f);
  float dv = t - mu;
  float var = wave_sum64(dv * dv) * (1.f / 64.f);
  float tn = dv * rsqrtf(var + EPS) * ugv + ubev;
  h_new[((size_t)i << 6) + lane] = hnl + fmaxf(tn, 0.f);
}

// ---------------- decoder: out = relu(h@dw1+db1)@dw2+db2 ----------------
__global__ __launch_bounds__(512) void decoder_kernel(
    const float* __restrict__ h,
    const float* __restrict__ dw1, const float* __restrict__ db1,
    const float* __restrict__ dw2, const float* __restrict__ db2,
    float* __restrict__ out) {
  __shared__ __align__(16) float w1s[64 * 32];
  __shared__ float w2s[64];
  __shared__ float b1s[32];
  __shared__ float hs[8][64];
  const int tid = threadIdx.x;
  const int lane = tid & 63;
  const int w = tid >> 6;

  for (int idx = tid; idx < 64 * 32; idx += 512) w1s[idx] = dw1[idx];
  if (tid < 64) w2s[tid] = dw2[tid];
  if (tid < 32) b1s[tid] = db1[tid];
  const float ob0 = db2[0], ob1 = db2[1];
  __syncthreads();

  const int total = B * N;
  const int per_iter = gridDim.x * 8;
  const int niter = (total + per_iter - 1) / per_iter;
  const int wave_global = blockIdx.x * 8 + w;

  for (int it = 0; it < niter; ++it) {
    const int i = it * per_iter + wave_global;
    if (i < total) {
      hs[w][lane] = h[((size_t)i << 6) + lane];
      float s1 = 0.f;
      if (lane < 32) {
        s1 = b1s[lane];
        for (int k = 0; k < 64; ++k) s1 = fmaf(hs[w][k], w1s[k * 32 + lane], s1);
        s1 = fmaxf(s1, 0.f);
      }
      float c0 = (lane < 32) ? s1 * w2s[lane * 2]     : 0.f;
      float c1 = (lane < 32) ? s1 * w2s[lane * 2 + 1] : 0.f;
#pragma unroll
      for (int off = 16; off > 0; off >>= 1) {
        c0 += __shfl_xor(c0, off, 64);
        c1 += __shfl_xor(c1, off, 64);
      }
      if (lane == 0) {
        out[(size_t)i * 2]     = c0 + ob0;
        out[(size_t)i * 2 + 1] = c1 + ob1;
      }
    }
  }
}

extern "C" void kernel_launch(void* const* d_in, const int* in_sizes, int n_in,
                              void* d_out, int out_size, void* d_ws, size_t ws_size,
                              hipStream_t stream) {
  const float* x        = (const float*)d_in[0];
  const int*   ei       = (const int*)d_in[1];
  const float* eattr    = (const float*)d_in[2];
  const float* enc_w    = (const float*)d_in[3];
  const float* enc_b    = (const float*)d_in[4];
  const float* msg_w1   = (const float*)d_in[5];
  const float* msg_b1   = (const float*)d_in[6];
  const float* msg_ln_g = (const float*)d_in[7];
  const float* msg_ln_b = (const float*)d_in[8];
  const float* msg_w2   = (const float*)d_in[9];
  const float* msg_b2   = (const float*)d_in[10];
  const float* up_w     = (const float*)d_in[11];
  const float* up_b     = (const float*)d_in[12];
  const float* up_ln_g  = (const float*)d_in[13];
  const float* up_ln_b  = (const float*)d_in[14];
  const float* dw1      = (const float*)d_in[15];
  const float* db1      = (const float*)d_in[16];
  const float* dw2      = (const float*)d_in[17];
  const float* db2      = (const float*)d_in[18];
  float* out = (float*)d_out;

  float* h0 = (float*)d_ws;
  float* h1 = h0 + (size_t)B * N * D;
  int* deg        = (int*)(h1 + (size_t)B * N * D);
  int* row_start  = deg + N;
  int* cursor     = row_start + N + 1;
  int* edge_order = cursor + N;

  const int* row = ei;       // edge_index[0]
  const int* col = ei + E;   // edge_index[1]

  // CSR build (deterministic up to within-node fp summation order)
  hipMemsetAsync(deg, 0, N * sizeof(int), stream);
  hist_kernel<<<(E + 255) / 256, 256, 0, stream>>>(row, deg);
  scan_kernel<<<1, 1024, 0, stream>>>(deg, row_start, cursor);
  scatter_kernel<<<(E + 255) / 256, 256, 0, stream>>>(row, cursor, edge_order);

  encoder_kernel<<<(B * N * D + 511) / 512, 512, 0, stream>>>(x, enc_w, enc_b, h0);

  float* bufs[2] = {h0, h1};
  for (int l = 0; l < L; ++l) {
    layer_kernel<<<(B * N + WPB - 1) / WPB, TPB, 0, stream>>>(
        bufs[l & 1], bufs[(l + 1) & 1], col, eattr, row_start, edge_order,
        msg_w1 + (size_t)l * 130 * 64, msg_b1 + l * 64,
        msg_ln_g + l * 64, msg_ln_b + l * 64,
        msg_w2 + (size_t)l * 64 * 64, msg_b2 + l * 64,
        up_w + (size_t)l * 128 * 64, up_b + l * 64,
        up_ln_g + l * 64, up_ln_b + l * 64);
  }

  decoder_kernel<<<512, 512, 0, stream>>>(bufs[L & 1], dw1, db1, dw2, db2, out);
}

// Round 3
// 9864.301 us; speedup vs baseline: 6.2890x; 2.4992x over previous
//
#include <hip/hip_runtime.h>

constexpr int N = 20000;
constexpr int E = 320000;
constexpr int B = 2;
constexpr int D = 64;
constexpr int L = 25;
constexpr float EPS = 1e-5f;

typedef __attribute__((ext_vector_type(8))) short short8;
typedef __attribute__((ext_vector_type(4))) float f32x4;

__device__ __forceinline__ unsigned short f2bf(float f) {
  unsigned u = __float_as_uint(f);
  u += 0x7fff + ((u >> 16) & 1);   // round-to-nearest-even
  return (unsigned short)(u >> 16);
}

__device__ __forceinline__ float wave_sum64(float v) {
#pragma unroll
  for (int off = 32; off > 0; off >>= 1) v += __shfl_xor(v, off, 64);
  return v;
}

// ---------------- CSR build (once per launch) ----------------
__global__ void hist_kernel(const int* __restrict__ row, int* __restrict__ deg) {
  int e = blockIdx.x * blockDim.x + threadIdx.x;
  if (e < E) atomicAdd(&deg[row[e]], 1);
}

__global__ __launch_bounds__(1024) void scan_kernel(const int* __restrict__ deg,
                                                    int* __restrict__ row_start,
                                                    int* __restrict__ cursor) {
  __shared__ int s[1024];
  const int t = threadIdx.x;
  constexpr int CH = (N + 1023) / 1024;
  int base = t * CH;
  int sum = 0;
  for (int k = 0; k < CH; ++k) {
    int idx = base + k;
    if (idx < N) sum += deg[idx];
  }
  s[t] = sum;
  __syncthreads();
  for (int off = 1; off < 1024; off <<= 1) {
    int v = (t >= off) ? s[t - off] : 0;
    __syncthreads();
    s[t] += v;
    __syncthreads();
  }
  int excl = s[t] - sum;
  for (int k = 0; k < CH; ++k) {
    int idx = base + k;
    if (idx < N) {
      row_start[idx] = excl;
      cursor[idx] = excl;
      excl += deg[idx];
    }
  }
  if (t == 1023) row_start[N] = s[1023];
}

__global__ void scatter_kernel(const int* __restrict__ row, int* __restrict__ cursor,
                               int* __restrict__ edge_order) {
  int e = blockIdx.x * blockDim.x + threadIdx.x;
  if (e < E) {
    int p = atomicAdd(&cursor[row[e]], 1);
    edge_order[p] = e;
  }
}

// ---------------- encoder ----------------
__global__ __launch_bounds__(512) void encoder_kernel(
    const float* __restrict__ x, const float* __restrict__ enc_w,
    const float* __restrict__ enc_b, float* __restrict__ h,
    unsigned short* __restrict__ hbf) {
  int idx = blockIdx.x * blockDim.x + threadIdx.x;
  if (idx >= B * N * D) return;
  int j = idx & (D - 1);
  int bn = idx >> 6;
  const float* xp = x + (size_t)bn * 3;
  float v = enc_b[j] + xp[0] * enc_w[j] + xp[1] * enc_w[D + j] + xp[2] * enc_w[2 * D + j];
  h[idx] = v;
  hbf[idx] = f2bf(v);
}

// ---------------- MFMA edge kernel ----------------
// Tiles of 16 sorted edges; GEMV1 via 16 mfma_16x16x32_bf16, LN in C-layout,
// P transposed through swizzled LDS, GEMV2 via 8 mfma, run-based atomic aggregation.
constexpr int EW = 8;       // waves per block
constexpr int ETPB = 512;
constexpr int TPG = E / 16; // tiles per graph = 20000

__global__ __launch_bounds__(ETPB) void edge_kernel(
    const unsigned short* __restrict__ hbf, float* __restrict__ aggr,
    const int* __restrict__ row, const int* __restrict__ col,
    const float* __restrict__ eattr, const int* __restrict__ edge_order,
    const float* __restrict__ w1, const float* __restrict__ b1,
    const float* __restrict__ g1, const float* __restrict__ be1,
    const float* __restrict__ w2, const float* __restrict__ b2) {
  __shared__ __align__(16) unsigned short w1f[16 * 512];  // 16 B-frags (ntile,ks)
  __shared__ __align__(16) unsigned short w2f[8 * 512];   // 8 B-frags (ntile,ks2)
  __shared__ __align__(16) char pbuf[EW][4096];           // per-wave: P(bf16 2KB) then mseg(f32 4KB)

  const int tid = threadIdx.x, lane = tid & 63, w = tid >> 6;
  const int cl = lane & 15, hg = lane >> 4;

  // stage w1 B-frags: frag f = ntile*4+ks; value = w1[k][n], k=ks*32+(ln>>4)*8+i, n=ntile*16+(ln&15)
  for (int idx = tid; idx < 16 * 512; idx += ETPB) {
    int f = idx >> 9, rem = idx & 511, ln = rem >> 3, i = rem & 7;
    int nt = f >> 2, ks = f & 3;
    int k = ks * 32 + (ln >> 4) * 8 + i, n = nt * 16 + (ln & 15);
    w1f[idx] = f2bf(w1[k * 64 + n]);
  }
  for (int idx = tid; idx < 8 * 512; idx += ETPB) {
    int f = idx >> 9, rem = idx & 511, ln = rem >> 3, i = rem & 7;
    int nt = f >> 1, ks = f & 1;
    int k = ks * 32 + (ln >> 4) * 8 + i, n = nt * 16 + (ln & 15);
    w2f[idx] = f2bf(w2[k * 64 + n]);
  }
  __syncthreads();

  // per-lane constants (channel c = nt*16+cl)
  float b1c[4], g1c[4], be1c[4], b2c[4], wA[4], wB[4];
#pragma unroll
  for (int nt = 0; nt < 4; ++nt) {
    int c = nt * 16 + cl;
    b1c[nt] = b1[c]; g1c[nt] = g1[c]; be1c[nt] = be1[c]; b2c[nt] = b2[c];
    wA[nt] = w1[128 * 64 + c]; wB[nt] = w1[129 * 64 + c];
  }

  const short8* w1v = (const short8*)w1f;
  const short8* w2v = (const short8*)w2f;

  const int wave_global = blockIdx.x * EW + w;
  const int nwaves = gridDim.x * EW;

  for (int t = wave_global; t < 2 * TPG; t += nwaves) {
    const int g = (t >= TPG) ? 1 : 0;
    const int tp = t - g * TPG;
    const int pos = tp * 16 + cl;
    const int eid = edge_order[pos];
    const int rv = row[eid], cv = col[eid];
    const float2 ea = *(const float2*)&eattr[2 * (size_t)eid];
    const unsigned short* hb = hbf + (size_t)g * N * 64;

    // A1 gather: lane holds edge cl, k-slice hg*8..hg*8+7 (+32) of h[row] / h[col]
    const unsigned short* pr = hb + ((size_t)rv << 6) + hg * 8;
    const unsigned short* pc = hb + ((size_t)cv << 6) + hg * 8;
    short8 av0 = *(const short8*)pr;
    short8 av1 = *(const short8*)(pr + 32);
    short8 av2 = *(const short8*)pc;
    short8 av3 = *(const short8*)(pc + 32);

    // GEMV1: acc[nt] over K=128
    f32x4 acc[4];
#pragma unroll
    for (int nt = 0; nt < 4; ++nt) acc[nt] = (f32x4){0.f, 0.f, 0.f, 0.f};
    short8 av[4] = {av0, av1, av2, av3};
#pragma unroll
    for (int ks = 0; ks < 4; ++ks) {
#pragma unroll
      for (int nt = 0; nt < 4; ++nt)
        acc[nt] = __builtin_amdgcn_mfma_f32_16x16x32_bf16(
            av[ks], w1v[(nt * 4 + ks) * 64 + lane], acc[nt], 0, 0, 0);
    }

    // fold bias + eattr rows (k=128,129); LN per edge; relu; write P (bf16, swizzled)
#pragma unroll
    for (int r = 0; r < 4; ++r) {
      float e0 = __shfl(ea.x, hg * 4 + r, 64);
      float e1 = __shfl(ea.y, hg * 4 + r, 64);
      float v[4];
#pragma unroll
      for (int nt = 0; nt < 4; ++nt)
        v[nt] = acc[nt][r] + b1c[nt] + e0 * wA[nt] + e1 * wB[nt];
      float sum = v[0] + v[1] + v[2] + v[3];
#pragma unroll
      for (int o = 1; o < 16; o <<= 1) sum += __shfl_xor(sum, o, 64);
      float mu = sum * (1.f / 64.f);
      float q = 0.f;
#pragma unroll
      for (int nt = 0; nt < 4; ++nt) { v[nt] -= mu; q += v[nt] * v[nt]; }
#pragma unroll
      for (int o = 1; o < 16; o <<= 1) q += __shfl_xor(q, o, 64);
      float rs = rsqrtf(q * (1.f / 64.f) + EPS);
      const int edge = hg * 4 + r;
#pragma unroll
      for (int nt = 0; nt < 4; ++nt) {
        float p = fmaxf(v[nt] * rs * g1c[nt] + be1c[nt], 0.f);
        unsigned byteoff = (unsigned)(edge * 128 + (nt * 16 + cl) * 2) ^ (unsigned)(hg << 5);
        *(unsigned short*)(&pbuf[w][byteoff]) = f2bf(p);
      }
    }

    // GEMV2: A = P[edge=cl][k], read swizzled; B = w2 frags
    f32x4 m[4];
#pragma unroll
    for (int nt = 0; nt < 4; ++nt) m[nt] = (f32x4){0.f, 0.f, 0.f, 0.f};
#pragma unroll
    for (int ks = 0; ks < 2; ++ks) {
      unsigned byteoff = (unsigned)(cl * 128 + (ks * 32 + hg * 8) * 2) ^ (unsigned)((cl >> 2) << 5);
      short8 a2 = *(const short8*)(&pbuf[w][byteoff]);
#pragma unroll
      for (int nt = 0; nt < 4; ++nt)
        m[nt] = __builtin_amdgcn_mfma_f32_16x16x32_bf16(
            a2, w2v[(nt * 2 + ks) * 64 + lane], m[nt], 0, 0, 0);
    }

    // + b2; stage messages f32 [16][64] (bank-swizzled) for segment sum
    float* ms = (float*)pbuf[w];
#pragma unroll
    for (int r = 0; r < 4; ++r) {
      const int edge = hg * 4 + r;
      const int swz = ((hg & 3) << 2) ^ ((hg & 1) << 4);
#pragma unroll
      for (int nt = 0; nt < 4; ++nt) {
        int c = nt * 16 + cl;
        ms[edge * 64 + (c ^ swz)] = m[nt][r] + b2c[nt];
      }
    }

    // segment sum over sorted rows; one 64-lane atomicAdd per run
    float* ag = aggr + (size_t)g * N * 64;
    float macc = 0.f;
    int rprev = __shfl(rv, 0, 64);
#pragma unroll
    for (int e = 0; e < 16; ++e) {
      int rcur = __shfl(rv, e, 64);
      if (rcur != rprev) {
        atomicAdd(&ag[((size_t)rprev << 6) + lane], macc);
        macc = 0.f;
        rprev = rcur;
      }
      const int eg = e >> 2;
      const int swz = ((eg & 3) << 2) ^ ((eg & 1) << 4);
      macc += ms[e * 64 + (lane ^ swz)];
    }
    atomicAdd(&ag[((size_t)rprev << 6) + lane], macc);
  }
}

// ---------------- node update: h += relu(LN([h,aggr]@uw+ub)), in place ----------------
constexpr int NW = 8;
constexpr int NTPB = 512;
constexpr int NPW = 4;

__global__ __launch_bounds__(NTPB) void node_kernel(
    float* __restrict__ h, unsigned short* __restrict__ hbf,
    const float* __restrict__ aggr,
    const float* __restrict__ uw, const float* __restrict__ ub,
    const float* __restrict__ ug, const float* __restrict__ ube) {
  __shared__ __align__(16) float wp[32 * 256];
  __shared__ __align__(16) float cat_s[NW][NPW][128];
  const int tid = threadIdx.x;
  const int lane = tid & 63;
  const int w = tid >> 6;

  for (int idx = tid; idx < 128 * 64; idx += NTPB) {
    int k = idx >> 6, j = idx & 63;
    wp[((k >> 2) << 8) + (j << 2) + (k & 3)] = uw[idx];
  }
  const float ubv = ub[lane], ugv = ug[lane], ubev = ube[lane];
  __syncthreads();

  const int total = B * N;
  const int per_iter = gridDim.x * NW * NPW;
  const int niter = (total + per_iter - 1) / per_iter;
  const int wave_global = blockIdx.x * NW + w;

  for (int it = 0; it < niter; ++it) {
    const int base = (it * gridDim.x * NW + wave_global) * NPW;
#pragma unroll
    for (int e = 0; e < NPW; ++e) {
      int i = base + e;
      if (i < total) {
        cat_s[w][e][lane]      = h[((size_t)i << 6) + lane];
        cat_s[w][e][64 + lane] = aggr[((size_t)i << 6) + lane];
      }
    }
    float t[NPW];
#pragma unroll
    for (int e = 0; e < NPW; ++e) t[e] = ubv;
    for (int k4 = 0; k4 < 32; ++k4) {
      const float4 wv = *(const float4*)&wp[(k4 << 8) + (lane << 2)];
#pragma unroll
      for (int e = 0; e < NPW; ++e) {
        const float4 cv = *(const float4*)&cat_s[w][e][k4 << 2];
        t[e] = fmaf(cv.x, wv.x, t[e]); t[e] = fmaf(cv.y, wv.y, t[e]);
        t[e] = fmaf(cv.z, wv.z, t[e]); t[e] = fmaf(cv.w, wv.w, t[e]);
      }
    }
#pragma unroll
    for (int e = 0; e < NPW; ++e) {
      float mu = wave_sum64(t[e]) * (1.f / 64.f);
      float dv = t[e] - mu;
      float var = wave_sum64(dv * dv) * (1.f / 64.f);
      float tn = dv * rsqrtf(var + EPS) * ugv + ubev;
      float u = fmaxf(tn, 0.f);
      int i = base + e;
      if (i < total) {
        float nv = cat_s[w][e][lane] + u;
        h[((size_t)i << 6) + lane] = nv;
        hbf[((size_t)i << 6) + lane] = f2bf(nv);
      }
    }
  }
}

// ---------------- decoder ----------------
__global__ __launch_bounds__(512) void decoder_kernel(
    const float* __restrict__ h,
    const float* __restrict__ dw1, const float* __restrict__ db1,
    const float* __restrict__ dw2, const float* __restrict__ db2,
    float* __restrict__ out) {
  __shared__ __align__(16) float w1s[64 * 32];
  __shared__ float w2s[64];
  __shared__ float b1s[32];
  __shared__ float hs[8][64];
  const int tid = threadIdx.x;
  const int lane = tid & 63;
  const int w = tid >> 6;

  for (int idx = tid; idx < 64 * 32; idx += 512) w1s[idx] = dw1[idx];
  if (tid < 64) w2s[tid] = dw2[tid];
  if (tid < 32) b1s[tid] = db1[tid];
  const float ob0 = db2[0], ob1 = db2[1];
  __syncthreads();

  const int total = B * N;
  const int per_iter = gridDim.x * 8;
  const int niter = (total + per_iter - 1) / per_iter;
  const int wave_global = blockIdx.x * 8 + w;

  for (int it = 0; it < niter; ++it) {
    const int i = it * per_iter + wave_global;
    if (i < total) {
      hs[w][lane] = h[((size_t)i << 6) + lane];
      float s1 = 0.f;
      if (lane < 32) {
        s1 = b1s[lane];
        for (int k = 0; k < 64; ++k) s1 = fmaf(hs[w][k], w1s[k * 32 + lane], s1);
        s1 = fmaxf(s1, 0.f);
      }
      float c0 = (lane < 32) ? s1 * w2s[lane * 2]     : 0.f;
      float c1 = (lane < 32) ? s1 * w2s[lane * 2 + 1] : 0.f;
#pragma unroll
      for (int off = 16; off > 0; off >>= 1) {
        c0 += __shfl_xor(c0, off, 64);
        c1 += __shfl_xor(c1, off, 64);
      }
      if (lane == 0) {
        out[(size_t)i * 2]     = c0 + ob0;
        out[(size_t)i * 2 + 1] = c1 + ob1;
      }
    }
  }
}

extern "C" void kernel_launch(void* const* d_in, const int* in_sizes, int n_in,
                              void* d_out, int out_size, void* d_ws, size_t ws_size,
                              hipStream_t stream) {
  const float* x        = (const float*)d_in[0];
  const int*   ei       = (const int*)d_in[1];
  const float* eattr    = (const float*)d_in[2];
  const float* enc_w    = (const float*)d_in[3];
  const float* enc_b    = (const float*)d_in[4];
  const float* msg_w1   = (const float*)d_in[5];
  const float* msg_b1   = (const float*)d_in[6];
  const float* msg_ln_g = (const float*)d_in[7];
  const float* msg_ln_b = (const float*)d_in[8];
  const float* msg_w2   = (const float*)d_in[9];
  const float* msg_b2   = (const float*)d_in[10];
  const float* up_w     = (const float*)d_in[11];
  const float* up_b     = (const float*)d_in[12];
  const float* up_ln_g  = (const float*)d_in[13];
  const float* up_ln_b  = (const float*)d_in[14];
  const float* dw1      = (const float*)d_in[15];
  const float* db1      = (const float*)d_in[16];
  const float* dw2      = (const float*)d_in[17];
  const float* db2      = (const float*)d_in[18];
  float* out = (float*)d_out;

  float* h            = (float*)d_ws;
  unsigned short* hbf = (unsigned short*)(h + (size_t)B * N * D);
  float* aggr         = (float*)(hbf + (size_t)B * N * D);
  int* deg        = (int*)(aggr + (size_t)B * N * D);
  int* row_start  = deg + N;
  int* cursor     = row_start + N + 1;
  int* edge_order = cursor + N;

  const int* row = ei;       // edge_index[0]
  const int* col = ei + E;   // edge_index[1]

  hipMemsetAsync(deg, 0, N * sizeof(int), stream);
  hist_kernel<<<(E + 255) / 256, 256, 0, stream>>>(row, deg);
  scan_kernel<<<1, 1024, 0, stream>>>(deg, row_start, cursor);
  scatter_kernel<<<(E + 255) / 256, 256, 0, stream>>>(row, cursor, edge_order);

  encoder_kernel<<<(B * N * D + 511) / 512, 512, 0, stream>>>(x, enc_w, enc_b, h, hbf);

  for (int l = 0; l < L; ++l) {
    hipMemsetAsync(aggr, 0, (size_t)B * N * D * sizeof(float), stream);
    edge_kernel<<<512, ETPB, 0, stream>>>(
        hbf, aggr, row, col, eattr, edge_order,
        msg_w1 + (size_t)l * 130 * 64, msg_b1 + l * 64,
        msg_ln_g + l * 64, msg_ln_b + l * 64,
        msg_w2 + (size_t)l * 64 * 64, msg_b2 + l * 64);
    node_kernel<<<256, NTPB, 0, stream>>>(
        h, hbf, aggr,
        up_w + (size_t)l * 128 * 64, up_b + l * 64,
        up_ln_g + l * 64, up_ln_b + l * 64);
  }

  decoder_kernel<<<512, 512, 0, stream>>>(h, dw1, db1, dw2, db2, out);
}